// Round 16
// baseline (232.702 us; speedup 1.0000x reference)
//
#include <hip/hip_runtime.h>
#include <stdint.h>
#include <stddef.h>

// ============================================================================
// MHA block on gfx950, bf16 MFMA pipeline.  B=2,S=2048,D=1024,H=16,hd=64.
// R21: flash l-sum via MFMA (ones-vector trick).  R20 counters: flash is the
// sole binding component (~49.7us, VALUBusy 51%, MfmaUtil 13.4%); per-tile
// VALU ~230 insts incl the ps-sum chain (14 adds + 2 ds_bpermute serial).
//  - l[m] = sum_t P[m][t] == MFMA(P-frag, ones):  l_acc f32x4 accumulated by
//    2 extra MFMAs/tile on the 13%-busy matrix pipe (free); deletes the
//    per-tile adds + cross-lane reduce + 4 epilogue shuffles.  Rescale on
//    non-skip reuses af4 (C-row mapping quad*4+r identical to Oacc).
//  - Everything else byte-identical to R20 (200.1us; best 200.1).
// Predictions: flash 49.7->46-48us (VALUBusy ~47%, MfmaUtil ~15%); total
// ~196-198us.  Neutral => session floor ~200us (no HW roofline: latency/
// occupancy-structural).
// MFMA layouts (verified m89/m91/m120):
//   A-frag: A[m=lane&15][k=(lane>>4)*8+j]  (16B/lane contiguous)
//   B-frag: B[k=(lane>>4)*8+j][n=lane&15] == row-major read of B^T tile
//   C/D:    col=lane&15, row=(lane>>4)*4+reg
// Tiled layout: addr(panel,kt,L) = ((panel*16+kt)*1024 + L)*8 shorts, with
//   L(row,kc) = (row>>4)*128 + kc*16 + (row&15), kc=(k&63)>>3.
// ============================================================================

typedef __bf16 bf16x8 __attribute__((ext_vector_type(8)));
typedef float  f32x4  __attribute__((ext_vector_type(4)));

__device__ __forceinline__ unsigned short f2b(float f) {
  union { float f; uint32_t u; } v; v.f = f;
  uint32_t u = v.u;
  return (unsigned short)((u + 0x7FFFu + ((u >> 16) & 1u)) >> 16);  // RNE
}

// HW packed f32->bf16 (RNE): dst[15:0]=bf16(lo), dst[31:16]=bf16(hi).
__device__ __forceinline__ uint32_t cvtpk(float lo, float hi) {
  uint32_t r;
  asm("v_cvt_pk_bf16_f32 %0, %1, %2" : "=v"(r) : "v"(lo), "v"(hi));
  return r;
}

// ---------------- fused cast: x, wq/wk/wv, wo -> bf16 frag-major tiled ----
__global__ void cast_all_kernel(const float* __restrict__ x,
                                const float* __restrict__ wq,
                                const float* __restrict__ wk,
                                const float* __restrict__ wv,
                                const float* __restrict__ wo,
                                unsigned short* __restrict__ xbf,
                                unsigned short* __restrict__ wqkv,
                                unsigned short* __restrict__ wobf) {
  int i = blockIdx.x * blockDim.x + threadIdx.x;   // 0..1048575
  const float* src;
  unsigned short* dst;
  int rem;
  if (i < 524288) {                // x: 32 panels x 16 kt x 1024 L
    src = x; dst = xbf; rem = i;
  } else if (i < 917504) {         // wqkv: 3 mats x 8 panels
    rem = i - 524288;
    const int mat = rem >> 17;
    src = (mat == 0) ? wq : (mat == 1) ? wk : wv;
    dst = wqkv;
  } else {                         // wo: 8 panels
    rem = i - 917504;
    src = wo; dst = wobf;
  }
  const int inmat = (i < 524288) ? rem : (i < 917504) ? (rem & 131071) : rem;
  const int L  = inmat & 1023;
  const int kt = (inmat >> 10) & 15;
  const int pn = inmat >> 14;
  const int row = pn * 128 + ((L >> 7) << 4) + (L & 15);
  const int k0  = kt * 64 + ((L >> 4) & 7) * 8;
  const float4* s = (const float4*)(src + (size_t)row * 1024 + k0);
  float4 a = s[0], b = s[1];
  uint4 pk;
  pk.x = (uint32_t)f2b(a.x) | ((uint32_t)f2b(a.y) << 16);
  pk.y = (uint32_t)f2b(a.z) | ((uint32_t)f2b(a.w) << 16);
  pk.z = (uint32_t)f2b(b.x) | ((uint32_t)f2b(b.y) << 16);
  pk.w = (uint32_t)f2b(b.z) | ((uint32_t)f2b(b.w) << 16);
  *(uint4*)(dst + (size_t)rem * 8) = pk;
}

// ---------------- fused QKV projection GEMM (+bias, +RoPE on q/k) ----------
// R20-proven: 3-set rotation (depth 2 halves) + XCD swizzle.  Grid dim3(768).
// Q output is PRE-SCALED by 0.125*log2(e) for flash's base-2 softmax.
__global__ __launch_bounds__(256, 3) void qkv_gemm_kernel(
    const unsigned short* __restrict__ A,    // x_bf TILED [32 pn][16 kt][1024 L][8]
    const unsigned short* __restrict__ W,    // wqkv TILED [24 pn][16 kt][1024 L][8]
    const float* __restrict__ biasq, const float* __restrict__ biask,
    const float* __restrict__ biasv,
    const float* __restrict__ cp, const float* __restrict__ sp,  // [2048][32]
    unsigned short* __restrict__ qo,
    unsigned short* __restrict__ ko,
    unsigned short* __restrict__ vo)
{
  constexpr float QSC = 0.18033688011f;      // 0.125 * log2(e)
  const int tid  = threadIdx.x;
  const int w    = tid >> 6, l = tid & 63;
  const int lm   = l & 15,  quad = l >> 4;
  // XCD-chunked 2D swizzle: each XCD (bid&7) owns an 8y x 12x region.
  const int bid  = blockIdx.x;               // 0..767
  const int xcd  = bid & 7, slot = bid >> 3; // slot 0..95
  const int by   = (xcd >> 1) * 8 + slot / 12;   // 0..31  (m-panel)
  const int nblk = (xcd & 1) * 12 + slot % 12;   // 0..23  (n-panel)
  const int m0   = by * 128;
  const int wm   = (w >> 1) * 64, wn = (w & 1) * 64;

  const unsigned short* At = A + (size_t)by * 16 * 8192;    // m-panel
  const unsigned short* Wt = W + (size_t)nblk * 16 * 8192;  // n-panel

  const f32x4 fzero = {0.f, 0.f, 0.f, 0.f};
  f32x4 acc[4][4];
#pragma unroll
  for (int i = 0; i < 4; ++i)
#pragma unroll
    for (int j = 0; j < 4; ++j) acc[i][j] = fzero;

  // three 8-frag sets; half h = tile (h>>1), kk = (h&1)
  bf16x8 aS0[4], bS0[4], aS1[4], bS1[4], aS2[4], bS2[4];

#define QKV_LOADH(DA, DB, H)                                                  \
  {                                                                           \
    const int T_ = (H) >> 1, KK_ = (H) & 1;                                   \
    const unsigned short* Ab_ = At + (size_t)T_ * 8192;                       \
    const unsigned short* Wb_ = Wt + (size_t)T_ * 8192;                       \
    _Pragma("unroll")                                                         \
    for (int i = 0; i < 4; ++i)                                               \
      DA[i] = *(const bf16x8*)(Ab_ +                                          \
          (size_t)((((w >> 1) * 4 + i) * 128 + KK_ * 64 + l)) * 8);           \
    _Pragma("unroll")                                                         \
    for (int j = 0; j < 4; ++j)                                               \
      DB[j] = *(const bf16x8*)(Wb_ +                                          \
          (size_t)((((w & 1) * 4 + j) * 128 + KK_ * 64 + l)) * 8);            \
  }

#define QKV_MFMAH(SA, SB)                                                     \
  _Pragma("unroll")                                                           \
  for (int i = 0; i < 4; ++i)                                                 \
    _Pragma("unroll")                                                         \
    for (int j = 0; j < 4; ++j)                                               \
      acc[i][j] = __builtin_amdgcn_mfma_f32_16x16x32_bf16(SA[i], SB[j],       \
                                                          acc[i][j], 0, 0, 0);

  QKV_LOADH(aS0, bS0, 0);
  QKV_LOADH(aS1, bS1, 1);
#pragma unroll 1
  for (int h = 0; h < 30; h += 3) {
    QKV_LOADH(aS2, bS2, h + 2); QKV_MFMAH(aS0, bS0);
    QKV_LOADH(aS0, bS0, h + 3); QKV_MFMAH(aS1, bS1);
    QKV_LOADH(aS1, bS1, h + 4); QKV_MFMAH(aS2, bS2);
  }
  QKV_MFMAH(aS0, bS0);                       // half 30
  QKV_MFMAH(aS1, bS1);                       // half 31
#undef QKV_LOADH
#undef QKV_MFMAH

  const int which = nblk >> 3;               // 0=q 1=k 2=v
  const int n0    = (nblk & 7) * 128;
  const float* bias = (which == 0) ? biasq : (which == 1) ? biask : biasv;
#pragma unroll
  for (int i = 0; i < 4; ++i) {
#pragma unroll
    for (int j = 0; j < 4; ++j) {
      const int n = n0 + wn + j * 16 + lm;
      const float bval = bias[n];
      const int h = n >> 6, d = n & 63;
      float vals[4];
#pragma unroll
      for (int r = 0; r < 4; ++r) {
        const int m = m0 + wm + i * 16 + quad * 4 + r;
        const int srow = m & 2047;
        float val = acc[i][j][r] + bval;
        if (which != 2) {
          const float c  = cp[srow * 32 + (d >> 1)];
          const float sn = sp[srow * 32 + (d >> 1)];
          const float part = __shfl_xor(val, 1, 64);
          val = (d & 1) ? (part * sn + val * c) : (val * c - part * sn);
        }
        vals[r] = val;
      }
      const int mbase = m0 + wm + i * 16 + quad * 4;   // 4 consecutive s
      const int b = mbase >> 11, s0 = mbase & 2047;
      const int bh = (b << 4) + h;
      if (which == 0) {
        // pre-scale q by QSC (commutes with RoPE; flash reads base-2 scores)
#pragma unroll
        for (int r = 0; r < 4; ++r)
          qo[((size_t)bh * 2048 + s0 + r) * 64 + d] = f2b(vals[r] * QSC);
      } else if (which == 1) {
        // tiled: base = (bh*32 + s>>6)*4096 + ((d>>3)*64 + (s&63))*8 + (d&7)
#pragma unroll
        for (int r = 0; r < 4; ++r) {
          const int s = s0 + r;
          ko[((size_t)bh * 32 + (s >> 6)) * 4096 +
             (size_t)(((d >> 3) * 64 + (s & 63))) * 8 + (d & 7)] = f2b(vals[r]);
        }
      } else {
        // V^T tiled, 4 consecutive s -> one uint2 (8B) store
        uint32_t w0 = (uint32_t)f2b(vals[0]) | ((uint32_t)f2b(vals[1]) << 16);
        uint32_t w1 = (uint32_t)f2b(vals[2]) | ((uint32_t)f2b(vals[3]) << 16);
        uint2 pk; pk.x = w0; pk.y = w1;
        *(uint2*)(vo + ((size_t)bh * 32 + (s0 >> 6)) * 4096 +
                  (size_t)((((s0 & 63) >> 3) * 64 + d)) * 8 + (s0 & 7)) = pk;
      }
    }
  }
}

// ---------------- flash attention (R21: l-sum via MFMA) -------------------
// grid (bh=32, 32); block 256 thr = 4 waves; block covers 64 q-rows.
// Barrier-free; K/V direct from global; mask only on diagonal tile;
// T13 defer-max; base-2 softmax (Q pre-scaled); cvt_pk P-pack;
// l accumulated by MFMA(P, ones) into f32x4 (C-row = quad*4+r).
__global__ __launch_bounds__(256, 4) void flash_kernel(
    const unsigned short* __restrict__ Q,    // [32][2048][64] row-major (pre-scaled)
    const unsigned short* __restrict__ K,    // tiled frag-major (see qkv)
    const unsigned short* __restrict__ VT,   // V^T tiled frag-major
    unsigned short* __restrict__ O)          // obf TILED [32 pn][16 kt][1024 L][8]
{
  constexpr int PSTRIDE = 72;                // Ps row stride (shorts)
  constexpr float THR = 11.5416f;            // 8 * log2(e)
  __shared__ unsigned short Ps[64 * PSTRIDE];    // 9 KB (only LDS)
  const int tid = threadIdx.x;
  const int w = tid >> 6, l = tid & 63, lm = l & 15, quad = l >> 4;
  const int bh = blockIdx.x, qt = 31 - (int)blockIdx.y;  // heavy first
  const int row0 = qt * 64 + w * 16;         // wave's first q-row

  // Q fragments: lane reads row row0+lm, 8 d at kc*32+quad*8
  bf16x8 aq[2];
#pragma unroll
  for (int kc = 0; kc < 2; ++kc)
    aq[kc] = *(const bf16x8*)(Q + ((size_t)bh * 2048 + row0 + lm) * 64 + kc * 32 + quad * 8);

  // all-ones B fragment for the l-sum MFMA
  bf16x8 ones;
#pragma unroll
  for (int i = 0; i < 8; ++i) ones[i] = (__bf16)1.0f;

  const f32x4 fzero = {0.f, 0.f, 0.f, 0.f};
  f32x4 Oacc[4];
#pragma unroll
  for (int jo = 0; jo < 4; ++jo) Oacc[jo] = fzero;
  f32x4 l_acc = fzero;                       // row sums, C-row = quad*4+r
  float m_i = -1e30f;

  const int nkv = qt + 1;

  // ---- unmasked tiles 0 .. qt-1 ----
#pragma unroll 1
  for (int kt = 0; kt < nkv - 1; ++kt) {
    const size_t tbase = ((size_t)bh * 32 + kt) * 4096;
    bf16x8 kf[2][4], vf[2][4];
#pragma unroll
    for (int kc = 0; kc < 2; ++kc)
#pragma unroll
      for (int tb = 0; tb < 4; ++tb) {
        const size_t off = tbase + (size_t)(((kc * 4 + quad) * 64 + tb * 16 + lm)) * 8;
        kf[kc][tb] = *(const bf16x8*)(K + off);
        vf[kc][tb] = *(const bf16x8*)(VT + off);
      }
    // S^T = K * Q^T : Sc[tb] holds t = tb*16+quad*4+r (rows), m = lm (col)
    // Scores are already in base-2 domain (Q pre-scaled).
    f32x4 Sc[4];
#pragma unroll
    for (int tb = 0; tb < 4; ++tb) Sc[tb] = fzero;
#pragma unroll
    for (int kc = 0; kc < 2; ++kc)
#pragma unroll
      for (int tb = 0; tb < 4; ++tb)
        Sc[tb] = __builtin_amdgcn_mfma_f32_16x16x32_bf16(kf[kc][tb], aq[kc], Sc[tb], 0, 0, 0);

    // max tree (shallow dependency)
    float mx;
    {
      float t0 = fmaxf(fmaxf(Sc[0][0], Sc[0][1]), fmaxf(Sc[0][2], Sc[0][3]));
      float t1 = fmaxf(fmaxf(Sc[1][0], Sc[1][1]), fmaxf(Sc[1][2], Sc[1][3]));
      float t2 = fmaxf(fmaxf(Sc[2][0], Sc[2][1]), fmaxf(Sc[2][2], Sc[2][3]));
      float t3 = fmaxf(fmaxf(Sc[3][0], Sc[3][1]), fmaxf(Sc[3][2], Sc[3][3]));
      mx = fmaxf(fmaxf(t0, t1), fmaxf(t2, t3));
    }
    mx = fmaxf(mx, __shfl_xor(mx, 16, 64));
    mx = fmaxf(mx, __shfl_xor(mx, 32, 64));

    // T13 defer-max: skip rescale when all rows grew by <= THR
    const bool skip = (bool)__all(mx - m_i <= THR);
    if (!skip) {
      const float mnew  = fmaxf(m_i, mx);
      const float alpha = exp2f(m_i - mnew);
      m_i = mnew;
      float af4[4];
#pragma unroll
      for (int r = 0; r < 4; ++r) af4[r] = __shfl(alpha, quad * 4 + r, 64);
#pragma unroll
      for (int jo = 0; jo < 4; ++jo)
#pragma unroll
        for (int r = 0; r < 4; ++r) Oacc[jo][r] *= af4[r];
#pragma unroll
      for (int r = 0; r < 4; ++r) l_acc[r] *= af4[r];
    }
    const float mref = m_i;

#pragma unroll
    for (int tb = 0; tb < 4; ++tb) {
      float p0 = exp2f(Sc[tb][0] - mref), p1 = exp2f(Sc[tb][1] - mref);
      float p2 = exp2f(Sc[tb][2] - mref), p3 = exp2f(Sc[tb][3] - mref);
      uint2 pk;
      pk.x = cvtpk(p0, p1);
      pk.y = cvtpk(p2, p3);
      *(uint2*)(Ps + (size_t)(w * 16 + lm) * PSTRIDE + tb * 16 + quad * 4) = pk;
    }

    // O += P V ; l_acc += P * ones  (row sums via MFMA, free pipe)
#pragma unroll
    for (int kc = 0; kc < 2; ++kc) {
      bf16x8 ap = *(const bf16x8*)(Ps + (size_t)(w * 16 + lm) * PSTRIDE + kc * 32 + quad * 8);
      l_acc = __builtin_amdgcn_mfma_f32_16x16x32_bf16(ap, ones, l_acc, 0, 0, 0);
#pragma unroll
      for (int jo = 0; jo < 4; ++jo)
        Oacc[jo] = __builtin_amdgcn_mfma_f32_16x16x32_bf16(ap, vf[kc][jo], Oacc[jo], 0, 0, 0);
    }
  }

  // ---- diagonal (masked) tile kt = qt ----
  {
    const size_t tbase = ((size_t)bh * 32 + qt) * 4096;
    bf16x8 kf[2][4], vf[2][4];
#pragma unroll
    for (int kc = 0; kc < 2; ++kc)
#pragma unroll
      for (int tb = 0; tb < 4; ++tb) {
        const size_t off = tbase + (size_t)(((kc * 4 + quad) * 64 + tb * 16 + lm)) * 8;
        kf[kc][tb] = *(const bf16x8*)(K + off);
        vf[kc][tb] = *(const bf16x8*)(VT + off);
      }
    f32x4 Sc[4];
#pragma unroll
    for (int tb = 0; tb < 4; ++tb) Sc[tb] = fzero;
#pragma unroll
    for (int kc = 0; kc < 2; ++kc)
#pragma unroll
      for (int tb = 0; tb < 4; ++tb)
        Sc[tb] = __builtin_amdgcn_mfma_f32_16x16x32_bf16(kf[kc][tb], aq[kc], Sc[tb], 0, 0, 0);

    const int mrel = w * 16 + lm;            // mask t-index > mrel
    float mx = -1e30f;
#pragma unroll
    for (int tb = 0; tb < 4; ++tb)
#pragma unroll
      for (int r = 0; r < 4; ++r) {
        float s = Sc[tb][r];
        if (tb * 16 + quad * 4 + r > mrel) s = -1e30f;
        Sc[tb][r] = s;
        mx = fmaxf(mx, s);
      }
    mx = fmaxf(mx, __shfl_xor(mx, 16, 64));
    mx = fmaxf(mx, __shfl_xor(mx, 32, 64));
    const float mnew  = fmaxf(m_i, mx);
    const float alpha = exp2f(m_i - mnew);
    m_i = mnew;

    float af4[4];
#pragma unroll
    for (int r = 0; r < 4; ++r) af4[r] = __shfl(alpha, quad * 4 + r, 64);
#pragma unroll
    for (int jo = 0; jo < 4; ++jo)
#pragma unroll
      for (int r = 0; r < 4; ++r) Oacc[jo][r] *= af4[r];
#pragma unroll
    for (int r = 0; r < 4; ++r) l_acc[r] *= af4[r];

#pragma unroll
    for (int tb = 0; tb < 4; ++tb) {
      float p0 = exp2f(Sc[tb][0] - mnew), p1 = exp2f(Sc[tb][1] - mnew);
      float p2 = exp2f(Sc[tb][2] - mnew), p3 = exp2f(Sc[tb][3] - mnew);
      uint2 pk;
      pk.x = cvtpk(p0, p1);
      pk.y = cvtpk(p2, p3);
      *(uint2*)(Ps + (size_t)(w * 16 + lm) * PSTRIDE + tb * 16 + quad * 4) = pk;
    }

#pragma unroll
    for (int kc = 0; kc < 2; ++kc) {
      bf16x8 ap = *(const bf16x8*)(Ps + (size_t)(w * 16 + lm) * PSTRIDE + kc * 32 + quad * 8);
      l_acc = __builtin_amdgcn_mfma_f32_16x16x32_bf16(ap, ones, l_acc, 0, 0, 0);
#pragma unroll
      for (int jo = 0; jo < 4; ++jo)
        Oacc[jo] = __builtin_amdgcn_mfma_f32_16x16x32_bf16(ap, vf[kc][jo], Oacc[jo], 0, 0, 0);
    }
  }

  // epilogue: normalize (l_acc already per C-row, no shuffles), write obf
  // TILED frag-major.  panel = b*16 + (qt>>1); kt = h;
  // L = ((qt&1)*4+w)*128 + (jo*2+(lm>>3))*16 + quad*4 + r; short = lm&7.
  float lf[4];
#pragma unroll
  for (int r = 0; r < 4; ++r) lf[r] = 1.0f / l_acc[r];
  const int b = bh >> 4, h = bh & 15;
  const size_t obase = ((size_t)((b * 16 + (qt >> 1)) * 16 + h)) * 8192;
  const int Lbase = ((qt & 1) * 4 + w) * 128 + quad * 4;
#pragma unroll
  for (int jo = 0; jo < 4; ++jo) {
    const int Ljo = Lbase + (jo * 2 + (lm >> 3)) * 16;
#pragma unroll
    for (int r = 0; r < 4; ++r)
      O[obase + (size_t)(Ljo + r) * 8 + (lm & 7)] = f2b(Oacc[jo][r] * lf[r]);
  }
}

// ---------------- output projection GEMM (R17-proven) ---------------------
// out[4096,1024] = Obf_tiled @ Wo_tiled^T + bias (fp32 out).
// LDS-free, barrier-free, 64x128 tiles, grid (8,64)=512 blocks (2/CU),
// ping-pong half-tile register pipeline.
__global__ __launch_bounds__(256, 2) void oproj_gemm_kernel(
    const unsigned short* __restrict__ A,    // obf TILED [32 pn][16 kt][1024 L][8]
    const unsigned short* __restrict__ W,    // wobf TILED [8 pn][16 kt][1024 L][8]
    const float* __restrict__ bias,
    float* __restrict__ out)
{
  const int tid = threadIdx.x;
  const int w = tid >> 6, l = tid & 63;
  const int lm = l & 15, quad = l >> 4;
  const int nblk = blockIdx.x;               // 0..7
  const int m0 = blockIdx.y * 64;            // 64-row m-tile
  const int half = blockIdx.y & 1;

  const unsigned short* At = A + (size_t)(blockIdx.y >> 1) * 16 * 8192;
  const unsigned short* Wt = W + (size_t)nblk * 16 * 8192;

  const f32x4 fzero = {0.f, 0.f, 0.f, 0.f};
  f32x4 acc[4][2];
#pragma unroll
  for (int i = 0; i < 4; ++i)
#pragma unroll
    for (int j = 0; j < 2; ++j) acc[i][j] = fzero;

  bf16x8 pA[4], pB[2], qA[4], qB[2];

#define OP_LOADH(DA, DB, T, KK)                                               \
  {                                                                           \
    const unsigned short* Ab_ = At + (size_t)(T) * 8192;                      \
    const unsigned short* Wb_ = Wt + (size_t)(T) * 8192;                      \
    _Pragma("unroll")                                                         \
    for (int i = 0; i < 4; ++i)                                               \
      DA[i] = *(const bf16x8*)(Ab_ +                                          \
          (size_t)(((half * 4 + i) * 128 + (KK) * 64 + l)) * 8);              \
    _Pragma("unroll")                                                         \
    for (int j = 0; j < 2; ++j)                                               \
      DB[j] = *(const bf16x8*)(Wb_ +                                          \
          (size_t)(((w * 2 + j) * 128 + (KK) * 64 + l)) * 8);                 \
  }

#define OP_MFMAH(SA, SB)                                                      \
  _Pragma("unroll")                                                           \
  for (int i = 0; i < 4; ++i)                                                 \
    _Pragma("unroll")                                                         \
    for (int j = 0; j < 2; ++j)                                               \
      acc[i][j] = __builtin_amdgcn_mfma_f32_16x16x32_bf16(SA[i], SB[j],       \
                                                          acc[i][j], 0, 0, 0);

  OP_LOADH(pA, pB, 0, 0);
#pragma unroll 1
  for (int t = 0; t < 16; ++t) {
    OP_LOADH(qA, qB, t, 1);
    OP_MFMAH(pA, pB);
    if (t < 15) OP_LOADH(pA, pB, t + 1, 0);
    OP_MFMAH(qA, qB);
  }
#undef OP_LOADH
#undef OP_MFMAH

#pragma unroll
  for (int i = 0; i < 4; ++i) {
#pragma unroll
    for (int j = 0; j < 2; ++j) {
      const int n = nblk * 128 + w * 32 + j * 16 + lm;
      const float bval = bias[n];
#pragma unroll
      for (int r = 0; r < 4; ++r) {
        const int m = m0 + i * 16 + quad * 4 + r;
        out[(size_t)m * 1024 + n] = acc[i][j][r] + bval;
      }
    }
  }
}

// ---------------- host launch ----------------
extern "C" void kernel_launch(void* const* d_in, const int* in_sizes, int n_in,
                              void* d_out, int out_size, void* d_ws, size_t ws_size,
                              hipStream_t stream) {
  (void)in_sizes; (void)n_in; (void)out_size; (void)ws_size;
  const float* x  = (const float*)d_in[0];
  const float* cp = (const float*)d_in[1];
  const float* sp = (const float*)d_in[2];
  const float* wq = (const float*)d_in[3];
  const float* bq = (const float*)d_in[4];
  const float* wk = (const float*)d_in[5];
  const float* bk = (const float*)d_in[6];
  const float* wv = (const float*)d_in[7];
  const float* bv = (const float*)d_in[8];
  const float* wo = (const float*)d_in[9];
  const float* bo = (const float*)d_in[10];
  float* out = (float*)d_out;

  unsigned short* xbf  = (unsigned short*)d_ws;          // 4M shorts (tiled)
  unsigned short* wqkv = xbf  + (size_t)4 * 1024 * 1024; // 3M (tiled)
  unsigned short* wobf = wqkv + (size_t)3 * 1024 * 1024; // 1M (tiled)
  unsigned short* qbf  = wobf + (size_t)1 * 1024 * 1024; // 4M (bh,s,d) pre-scaled
  unsigned short* kbf  = qbf  + (size_t)4 * 1024 * 1024; // 4M (tiled frag-major)
  unsigned short* vbf  = kbf  + (size_t)4 * 1024 * 1024; // 4M (V^T tiled)
  unsigned short* obf  = vbf  + (size_t)4 * 1024 * 1024; // 4M (tiled frag-major)

  hipLaunchKernelGGL(cast_all_kernel, dim3(4096), dim3(256), 0, stream,
                     x, wq, wk, wv, wo, xbf, wqkv, wobf);

  hipLaunchKernelGGL(qkv_gemm_kernel, dim3(768), dim3(256), 0, stream,
                     xbf, wqkv, bq, bk, bv, cp, sp, qbf, kbf, vbf);
  hipLaunchKernelGGL(flash_kernel, dim3(32, 32), dim3(256), 0, stream,
                     qbf, kbf, vbf, obf);
  hipLaunchKernelGGL(oproj_gemm_kernel, dim3(8, 64), dim3(256), 0, stream,
                     obf, wobf, bo, out);
}

// Round 17
// 199.561 us; speedup vs baseline: 1.1661x; 1.1661x over previous
//
#include <hip/hip_runtime.h>
#include <stdint.h>
#include <stddef.h>

// ============================================================================
// MHA block on gfx950, bf16 MFMA pipeline.  B=2,S=2048,D=1024,H=16,hd=64.
// R22 == R20 revert (verified 200.1us).  R21's l-sum-via-MFMA regressed
// flash 49.7->77us: VGPR 64->52 with MfmaUtil/VALUBusy falling proportionally
// = scheduler shortened load live-ranges (de-pipelined K/V prefetch) when the
// extra MFMAs + l_acc MFMA->VALU round-trip raised pressure.  Reverted.
// Session ladder: 237 (anchor) -> 226.7 (R14 flash TLP+defer-max) -> 223.9
// (R15 qkv tiled-direct) -> 209.8 (R16 qkv reg ping-pong) -> 200.3 (R17
// oproj port + cast fuse) -> 200.1 (R20 qkv 3-set rotation + prescaled Q).
// Structure: all GEMMs LDS-free/barrier-free on frag-major tiled layouts
// with register-rotation pipelines; flash barrier-free with direct K/V
// reads, base-2 softmax, defer-max, cvt_pk P-pack.
// MFMA layouts (verified m89/m91/m120):
//   A-frag: A[m=lane&15][k=(lane>>4)*8+j]  (16B/lane contiguous)
//   B-frag: B[k=(lane>>4)*8+j][n=lane&15] == row-major read of B^T tile
//   C/D:    col=lane&15, row=(lane>>4)*4+reg
// Tiled layout: addr(panel,kt,L) = ((panel*16+kt)*1024 + L)*8 shorts, with
//   L(row,kc) = (row>>4)*128 + kc*16 + (row&15), kc=(k&63)>>3.
// ============================================================================

typedef __bf16 bf16x8 __attribute__((ext_vector_type(8)));
typedef float  f32x4  __attribute__((ext_vector_type(4)));

__device__ __forceinline__ unsigned short f2b(float f) {
  union { float f; uint32_t u; } v; v.f = f;
  uint32_t u = v.u;
  return (unsigned short)((u + 0x7FFFu + ((u >> 16) & 1u)) >> 16);  // RNE
}

// HW packed f32->bf16 (RNE): dst[15:0]=bf16(lo), dst[31:16]=bf16(hi).
__device__ __forceinline__ uint32_t cvtpk(float lo, float hi) {
  uint32_t r;
  asm("v_cvt_pk_bf16_f32 %0, %1, %2" : "=v"(r) : "v"(lo), "v"(hi));
  return r;
}

// ---------------- fused cast: x, wq/wk/wv, wo -> bf16 frag-major tiled ----
__global__ void cast_all_kernel(const float* __restrict__ x,
                                const float* __restrict__ wq,
                                const float* __restrict__ wk,
                                const float* __restrict__ wv,
                                const float* __restrict__ wo,
                                unsigned short* __restrict__ xbf,
                                unsigned short* __restrict__ wqkv,
                                unsigned short* __restrict__ wobf) {
  int i = blockIdx.x * blockDim.x + threadIdx.x;   // 0..1048575
  const float* src;
  unsigned short* dst;
  int rem;
  if (i < 524288) {                // x: 32 panels x 16 kt x 1024 L
    src = x; dst = xbf; rem = i;
  } else if (i < 917504) {         // wqkv: 3 mats x 8 panels
    rem = i - 524288;
    const int mat = rem >> 17;
    src = (mat == 0) ? wq : (mat == 1) ? wk : wv;
    dst = wqkv;
  } else {                         // wo: 8 panels
    rem = i - 917504;
    src = wo; dst = wobf;
  }
  const int inmat = (i < 524288) ? rem : (i < 917504) ? (rem & 131071) : rem;
  const int L  = inmat & 1023;
  const int kt = (inmat >> 10) & 15;
  const int pn = inmat >> 14;
  const int row = pn * 128 + ((L >> 7) << 4) + (L & 15);
  const int k0  = kt * 64 + ((L >> 4) & 7) * 8;
  const float4* s = (const float4*)(src + (size_t)row * 1024 + k0);
  float4 a = s[0], b = s[1];
  uint4 pk;
  pk.x = (uint32_t)f2b(a.x) | ((uint32_t)f2b(a.y) << 16);
  pk.y = (uint32_t)f2b(a.z) | ((uint32_t)f2b(a.w) << 16);
  pk.z = (uint32_t)f2b(b.x) | ((uint32_t)f2b(b.y) << 16);
  pk.w = (uint32_t)f2b(b.z) | ((uint32_t)f2b(b.w) << 16);
  *(uint4*)(dst + (size_t)rem * 8) = pk;
}

// ---------------- fused QKV projection GEMM (+bias, +RoPE on q/k) ----------
// 3-set rotation (depth 2 halves) + XCD-chunked swizzle.  Grid dim3(768).
// Q output is PRE-SCALED by 0.125*log2(e) for flash's base-2 softmax.
__global__ __launch_bounds__(256, 3) void qkv_gemm_kernel(
    const unsigned short* __restrict__ A,    // x_bf TILED [32 pn][16 kt][1024 L][8]
    const unsigned short* __restrict__ W,    // wqkv TILED [24 pn][16 kt][1024 L][8]
    const float* __restrict__ biasq, const float* __restrict__ biask,
    const float* __restrict__ biasv,
    const float* __restrict__ cp, const float* __restrict__ sp,  // [2048][32]
    unsigned short* __restrict__ qo,
    unsigned short* __restrict__ ko,
    unsigned short* __restrict__ vo)
{
  constexpr float QSC = 0.18033688011f;      // 0.125 * log2(e)
  const int tid  = threadIdx.x;
  const int w    = tid >> 6, l = tid & 63;
  const int lm   = l & 15,  quad = l >> 4;
  // XCD-chunked 2D swizzle: each XCD (bid&7) owns an 8y x 12x region.
  const int bid  = blockIdx.x;               // 0..767
  const int xcd  = bid & 7, slot = bid >> 3; // slot 0..95
  const int by   = (xcd >> 1) * 8 + slot / 12;   // 0..31  (m-panel)
  const int nblk = (xcd & 1) * 12 + slot % 12;   // 0..23  (n-panel)
  const int m0   = by * 128;
  const int wm   = (w >> 1) * 64, wn = (w & 1) * 64;

  const unsigned short* At = A + (size_t)by * 16 * 8192;    // m-panel
  const unsigned short* Wt = W + (size_t)nblk * 16 * 8192;  // n-panel

  const f32x4 fzero = {0.f, 0.f, 0.f, 0.f};
  f32x4 acc[4][4];
#pragma unroll
  for (int i = 0; i < 4; ++i)
#pragma unroll
    for (int j = 0; j < 4; ++j) acc[i][j] = fzero;

  // three 8-frag sets; half h = tile (h>>1), kk = (h&1)
  bf16x8 aS0[4], bS0[4], aS1[4], bS1[4], aS2[4], bS2[4];

#define QKV_LOADH(DA, DB, H)                                                  \
  {                                                                           \
    const int T_ = (H) >> 1, KK_ = (H) & 1;                                   \
    const unsigned short* Ab_ = At + (size_t)T_ * 8192;                       \
    const unsigned short* Wb_ = Wt + (size_t)T_ * 8192;                       \
    _Pragma("unroll")                                                         \
    for (int i = 0; i < 4; ++i)                                               \
      DA[i] = *(const bf16x8*)(Ab_ +                                          \
          (size_t)((((w >> 1) * 4 + i) * 128 + KK_ * 64 + l)) * 8);           \
    _Pragma("unroll")                                                         \
    for (int j = 0; j < 4; ++j)                                               \
      DB[j] = *(const bf16x8*)(Wb_ +                                          \
          (size_t)((((w & 1) * 4 + j) * 128 + KK_ * 64 + l)) * 8);            \
  }

#define QKV_MFMAH(SA, SB)                                                     \
  _Pragma("unroll")                                                           \
  for (int i = 0; i < 4; ++i)                                                 \
    _Pragma("unroll")                                                         \
    for (int j = 0; j < 4; ++j)                                               \
      acc[i][j] = __builtin_amdgcn_mfma_f32_16x16x32_bf16(SA[i], SB[j],       \
                                                          acc[i][j], 0, 0, 0);

  QKV_LOADH(aS0, bS0, 0);
  QKV_LOADH(aS1, bS1, 1);
#pragma unroll 1
  for (int h = 0; h < 30; h += 3) {
    QKV_LOADH(aS2, bS2, h + 2); QKV_MFMAH(aS0, bS0);
    QKV_LOADH(aS0, bS0, h + 3); QKV_MFMAH(aS1, bS1);
    QKV_LOADH(aS1, bS1, h + 4); QKV_MFMAH(aS2, bS2);
  }
  QKV_MFMAH(aS0, bS0);                       // half 30
  QKV_MFMAH(aS1, bS1);                       // half 31
#undef QKV_LOADH
#undef QKV_MFMAH

  const int which = nblk >> 3;               // 0=q 1=k 2=v
  const int n0    = (nblk & 7) * 128;
  const float* bias = (which == 0) ? biasq : (which == 1) ? biask : biasv;
#pragma unroll
  for (int i = 0; i < 4; ++i) {
#pragma unroll
    for (int j = 0; j < 4; ++j) {
      const int n = n0 + wn + j * 16 + lm;
      const float bval = bias[n];
      const int h = n >> 6, d = n & 63;
      float vals[4];
#pragma unroll
      for (int r = 0; r < 4; ++r) {
        const int m = m0 + wm + i * 16 + quad * 4 + r;
        const int srow = m & 2047;
        float val = acc[i][j][r] + bval;
        if (which != 2) {
          const float c  = cp[srow * 32 + (d >> 1)];
          const float sn = sp[srow * 32 + (d >> 1)];
          const float part = __shfl_xor(val, 1, 64);
          val = (d & 1) ? (part * sn + val * c) : (val * c - part * sn);
        }
        vals[r] = val;
      }
      const int mbase = m0 + wm + i * 16 + quad * 4;   // 4 consecutive s
      const int b = mbase >> 11, s0 = mbase & 2047;
      const int bh = (b << 4) + h;
      if (which == 0) {
        // pre-scale q by QSC (commutes with RoPE; flash reads base-2 scores)
#pragma unroll
        for (int r = 0; r < 4; ++r)
          qo[((size_t)bh * 2048 + s0 + r) * 64 + d] = f2b(vals[r] * QSC);
      } else if (which == 1) {
        // tiled: base = (bh*32 + s>>6)*4096 + ((d>>3)*64 + (s&63))*8 + (d&7)
#pragma unroll
        for (int r = 0; r < 4; ++r) {
          const int s = s0 + r;
          ko[((size_t)bh * 32 + (s >> 6)) * 4096 +
             (size_t)(((d >> 3) * 64 + (s & 63))) * 8 + (d & 7)] = f2b(vals[r]);
        }
      } else {
        // V^T tiled, 4 consecutive s -> one uint2 (8B) store
        uint32_t w0 = (uint32_t)f2b(vals[0]) | ((uint32_t)f2b(vals[1]) << 16);
        uint32_t w1 = (uint32_t)f2b(vals[2]) | ((uint32_t)f2b(vals[3]) << 16);
        uint2 pk; pk.x = w0; pk.y = w1;
        *(uint2*)(vo + ((size_t)bh * 32 + (s0 >> 6)) * 4096 +
                  (size_t)((((s0 & 63) >> 3) * 64 + d)) * 8 + (s0 & 7)) = pk;
      }
    }
  }
}

// ---------------- flash attention (pre-scaled Q, base-2 softmax) ----------
// grid (bh=32, 32); block 256 thr = 4 waves; block covers 64 q-rows.
// Barrier-free; K/V direct from global; mask only on diagonal tile;
// T13 defer-max; cvt_pk P-pack.
__global__ __launch_bounds__(256, 4) void flash_kernel(
    const unsigned short* __restrict__ Q,    // [32][2048][64] row-major (pre-scaled)
    const unsigned short* __restrict__ K,    // tiled frag-major (see qkv)
    const unsigned short* __restrict__ VT,   // V^T tiled frag-major
    unsigned short* __restrict__ O)          // obf TILED [32 pn][16 kt][1024 L][8]
{
  constexpr int PSTRIDE = 72;                // Ps row stride (shorts)
  constexpr float THR = 11.5416f;            // 8 * log2(e)
  __shared__ unsigned short Ps[64 * PSTRIDE];    // 9 KB (only LDS)
  const int tid = threadIdx.x;
  const int w = tid >> 6, l = tid & 63, lm = l & 15, quad = l >> 4;
  const int bh = blockIdx.x, qt = 31 - (int)blockIdx.y;  // heavy first
  const int row0 = qt * 64 + w * 16;         // wave's first q-row

  // Q fragments: lane reads row row0+lm, 8 d at kc*32+quad*8
  bf16x8 aq[2];
#pragma unroll
  for (int kc = 0; kc < 2; ++kc)
    aq[kc] = *(const bf16x8*)(Q + ((size_t)bh * 2048 + row0 + lm) * 64 + kc * 32 + quad * 8);

  const f32x4 fzero = {0.f, 0.f, 0.f, 0.f};
  f32x4 Oacc[4];
#pragma unroll
  for (int jo = 0; jo < 4; ++jo) Oacc[jo] = fzero;
  float m_i = -1e30f, l_i = 0.f;

  const int nkv = qt + 1;

  // ---- unmasked tiles 0 .. qt-1 ----
#pragma unroll 1
  for (int kt = 0; kt < nkv - 1; ++kt) {
    const size_t tbase = ((size_t)bh * 32 + kt) * 4096;
    bf16x8 kf[2][4], vf[2][4];
#pragma unroll
    for (int kc = 0; kc < 2; ++kc)
#pragma unroll
      for (int tb = 0; tb < 4; ++tb) {
        const size_t off = tbase + (size_t)(((kc * 4 + quad) * 64 + tb * 16 + lm)) * 8;
        kf[kc][tb] = *(const bf16x8*)(K + off);
        vf[kc][tb] = *(const bf16x8*)(VT + off);
      }
    // S^T = K * Q^T : Sc[tb] holds t = tb*16+quad*4+r (rows), m = lm (col)
    // Scores are already in base-2 domain (Q pre-scaled).
    f32x4 Sc[4];
#pragma unroll
    for (int tb = 0; tb < 4; ++tb) Sc[tb] = fzero;
#pragma unroll
    for (int kc = 0; kc < 2; ++kc)
#pragma unroll
      for (int tb = 0; tb < 4; ++tb)
        Sc[tb] = __builtin_amdgcn_mfma_f32_16x16x32_bf16(kf[kc][tb], aq[kc], Sc[tb], 0, 0, 0);

    // max tree (shallow dependency)
    float mx;
    {
      float t0 = fmaxf(fmaxf(Sc[0][0], Sc[0][1]), fmaxf(Sc[0][2], Sc[0][3]));
      float t1 = fmaxf(fmaxf(Sc[1][0], Sc[1][1]), fmaxf(Sc[1][2], Sc[1][3]));
      float t2 = fmaxf(fmaxf(Sc[2][0], Sc[2][1]), fmaxf(Sc[2][2], Sc[2][3]));
      float t3 = fmaxf(fmaxf(Sc[3][0], Sc[3][1]), fmaxf(Sc[3][2], Sc[3][3]));
      mx = fmaxf(fmaxf(t0, t1), fmaxf(t2, t3));
    }
    mx = fmaxf(mx, __shfl_xor(mx, 16, 64));
    mx = fmaxf(mx, __shfl_xor(mx, 32, 64));

    // T13 defer-max: skip rescale when all rows grew by <= THR
    const bool skip = (bool)__all(mx - m_i <= THR);
    float alpha = 1.f;
    if (!skip) {
      const float mnew = fmaxf(m_i, mx);
      alpha = exp2f(m_i - mnew);
      m_i = mnew;
    }
    const float mref = m_i;

    float ps = 0.f;
#pragma unroll
    for (int tb = 0; tb < 4; ++tb) {
      float p0 = exp2f(Sc[tb][0] - mref), p1 = exp2f(Sc[tb][1] - mref);
      float p2 = exp2f(Sc[tb][2] - mref), p3 = exp2f(Sc[tb][3] - mref);
      ps += (p0 + p1) + (p2 + p3);
      uint2 pk;
      pk.x = cvtpk(p0, p1);
      pk.y = cvtpk(p2, p3);
      *(uint2*)(Ps + (size_t)(w * 16 + lm) * PSTRIDE + tb * 16 + quad * 4) = pk;
    }
    ps += __shfl_xor(ps, 16, 64);
    ps += __shfl_xor(ps, 32, 64);
    if (skip) {
      l_i += ps;
    } else {
      l_i = l_i * alpha + ps;
      float af4[4];
#pragma unroll
      for (int r = 0; r < 4; ++r) af4[r] = __shfl(alpha, quad * 4 + r, 64);
#pragma unroll
      for (int jo = 0; jo < 4; ++jo)
#pragma unroll
        for (int r = 0; r < 4; ++r) Oacc[jo][r] *= af4[r];
    }

    // O += P V
#pragma unroll
    for (int kc = 0; kc < 2; ++kc) {
      bf16x8 ap = *(const bf16x8*)(Ps + (size_t)(w * 16 + lm) * PSTRIDE + kc * 32 + quad * 8);
#pragma unroll
      for (int jo = 0; jo < 4; ++jo)
        Oacc[jo] = __builtin_amdgcn_mfma_f32_16x16x32_bf16(ap, vf[kc][jo], Oacc[jo], 0, 0, 0);
    }
  }

  // ---- diagonal (masked) tile kt = qt ----
  {
    const size_t tbase = ((size_t)bh * 32 + qt) * 4096;
    bf16x8 kf[2][4], vf[2][4];
#pragma unroll
    for (int kc = 0; kc < 2; ++kc)
#pragma unroll
      for (int tb = 0; tb < 4; ++tb) {
        const size_t off = tbase + (size_t)(((kc * 4 + quad) * 64 + tb * 16 + lm)) * 8;
        kf[kc][tb] = *(const bf16x8*)(K + off);
        vf[kc][tb] = *(const bf16x8*)(VT + off);
      }
    f32x4 Sc[4];
#pragma unroll
    for (int tb = 0; tb < 4; ++tb) Sc[tb] = fzero;
#pragma unroll
    for (int kc = 0; kc < 2; ++kc)
#pragma unroll
      for (int tb = 0; tb < 4; ++tb)
        Sc[tb] = __builtin_amdgcn_mfma_f32_16x16x32_bf16(kf[kc][tb], aq[kc], Sc[tb], 0, 0, 0);

    const int mrel = w * 16 + lm;            // mask t-index > mrel
    float mx = -1e30f;
#pragma unroll
    for (int tb = 0; tb < 4; ++tb)
#pragma unroll
      for (int r = 0; r < 4; ++r) {
        float s = Sc[tb][r];
        if (tb * 16 + quad * 4 + r > mrel) s = -1e30f;
        Sc[tb][r] = s;
        mx = fmaxf(mx, s);
      }
    mx = fmaxf(mx, __shfl_xor(mx, 16, 64));
    mx = fmaxf(mx, __shfl_xor(mx, 32, 64));
    const float mnew  = fmaxf(m_i, mx);
    const float alpha = exp2f(m_i - mnew);
    m_i = mnew;

    float ps = 0.f;
#pragma unroll
    for (int tb = 0; tb < 4; ++tb) {
      float p0 = exp2f(Sc[tb][0] - mnew), p1 = exp2f(Sc[tb][1] - mnew);
      float p2 = exp2f(Sc[tb][2] - mnew), p3 = exp2f(Sc[tb][3] - mnew);
      ps += (p0 + p1) + (p2 + p3);
      uint2 pk;
      pk.x = cvtpk(p0, p1);
      pk.y = cvtpk(p2, p3);
      *(uint2*)(Ps + (size_t)(w * 16 + lm) * PSTRIDE + tb * 16 + quad * 4) = pk;
    }
    ps += __shfl_xor(ps, 16, 64);
    ps += __shfl_xor(ps, 32, 64);
    l_i = l_i * alpha + ps;

    float af4[4];
#pragma unroll
    for (int r = 0; r < 4; ++r) af4[r] = __shfl(alpha, quad * 4 + r, 64);
#pragma unroll
    for (int jo = 0; jo < 4; ++jo)
#pragma unroll
      for (int r = 0; r < 4; ++r) Oacc[jo][r] *= af4[r];

#pragma unroll
    for (int kc = 0; kc < 2; ++kc) {
      bf16x8 ap = *(const bf16x8*)(Ps + (size_t)(w * 16 + lm) * PSTRIDE + kc * 32 + quad * 8);
#pragma unroll
      for (int jo = 0; jo < 4; ++jo)
        Oacc[jo] = __builtin_amdgcn_mfma_f32_16x16x32_bf16(ap, vf[kc][jo], Oacc[jo], 0, 0, 0);
    }
  }

  // epilogue: normalize, write obf TILED frag-major.
  // panel = b*16 + (qt>>1); kt = h; L = ((qt&1)*4+w)*128 + (jo*2+(lm>>3))*16
  //         + quad*4 + r; short = lm&7.
  float lf[4];
#pragma unroll
  for (int r = 0; r < 4; ++r) lf[r] = 1.0f / __shfl(l_i, quad * 4 + r, 64);
  const int b = bh >> 4, h = bh & 15;
  const size_t obase = ((size_t)((b * 16 + (qt >> 1)) * 16 + h)) * 8192;
  const int Lbase = ((qt & 1) * 4 + w) * 128 + quad * 4;
#pragma unroll
  for (int jo = 0; jo < 4; ++jo) {
    const int Ljo = Lbase + (jo * 2 + (lm >> 3)) * 16;
#pragma unroll
    for (int r = 0; r < 4; ++r)
      O[obase + (size_t)(Ljo + r) * 8 + (lm & 7)] = f2b(Oacc[jo][r] * lf[r]);
  }
}

// ---------------- output projection GEMM ----------------------------------
// out[4096,1024] = Obf_tiled @ Wo_tiled^T + bias (fp32 out).
// LDS-free, barrier-free, 64x128 tiles, grid (8,64)=512 blocks (2/CU),
// ping-pong half-tile register pipeline.
__global__ __launch_bounds__(256, 2) void oproj_gemm_kernel(
    const unsigned short* __restrict__ A,    // obf TILED [32 pn][16 kt][1024 L][8]
    const unsigned short* __restrict__ W,    // wobf TILED [8 pn][16 kt][1024 L][8]
    const float* __restrict__ bias,
    float* __restrict__ out)
{
  const int tid = threadIdx.x;
  const int w = tid >> 6, l = tid & 63;
  const int lm = l & 15, quad = l >> 4;
  const int nblk = blockIdx.x;               // 0..7
  const int m0 = blockIdx.y * 64;            // 64-row m-tile
  const int half = blockIdx.y & 1;

  const unsigned short* At = A + (size_t)(blockIdx.y >> 1) * 16 * 8192;
  const unsigned short* Wt = W + (size_t)nblk * 16 * 8192;

  const f32x4 fzero = {0.f, 0.f, 0.f, 0.f};
  f32x4 acc[4][2];
#pragma unroll
  for (int i = 0; i < 4; ++i)
#pragma unroll
    for (int j = 0; j < 2; ++j) acc[i][j] = fzero;

  bf16x8 pA[4], pB[2], qA[4], qB[2];

#define OP_LOADH(DA, DB, T, KK)                                               \
  {                                                                           \
    const unsigned short* Ab_ = At + (size_t)(T) * 8192;                      \
    const unsigned short* Wb_ = Wt + (size_t)(T) * 8192;                      \
    _Pragma("unroll")                                                         \
    for (int i = 0; i < 4; ++i)                                               \
      DA[i] = *(const bf16x8*)(Ab_ +                                          \
          (size_t)(((half * 4 + i) * 128 + (KK) * 64 + l)) * 8);              \
    _Pragma("unroll")                                                         \
    for (int j = 0; j < 2; ++j)                                               \
      DB[j] = *(const bf16x8*)(Wb_ +                                          \
          (size_t)(((w * 2 + j) * 128 + (KK) * 64 + l)) * 8);                 \
  }

#define OP_MFMAH(SA, SB)                                                      \
  _Pragma("unroll")                                                           \
  for (int i = 0; i < 4; ++i)                                                 \
    _Pragma("unroll")                                                         \
    for (int j = 0; j < 2; ++j)                                               \
      acc[i][j] = __builtin_amdgcn_mfma_f32_16x16x32_bf16(SA[i], SB[j],       \
                                                          acc[i][j], 0, 0, 0);

  OP_LOADH(pA, pB, 0, 0);
#pragma unroll 1
  for (int t = 0; t < 16; ++t) {
    OP_LOADH(qA, qB, t, 1);
    OP_MFMAH(pA, pB);
    if (t < 15) OP_LOADH(pA, pB, t + 1, 0);
    OP_MFMAH(qA, qB);
  }
#undef OP_LOADH
#undef OP_MFMAH

#pragma unroll
  for (int i = 0; i < 4; ++i) {
#pragma unroll
    for (int j = 0; j < 2; ++j) {
      const int n = nblk * 128 + w * 32 + j * 16 + lm;
      const float bval = bias[n];
#pragma unroll
      for (int r = 0; r < 4; ++r) {
        const int m = m0 + i * 16 + quad * 4 + r;
        out[(size_t)m * 1024 + n] = acc[i][j][r] + bval;
      }
    }
  }
}

// ---------------- host launch ----------------
extern "C" void kernel_launch(void* const* d_in, const int* in_sizes, int n_in,
                              void* d_out, int out_size, void* d_ws, size_t ws_size,
                              hipStream_t stream) {
  (void)in_sizes; (void)n_in; (void)out_size; (void)ws_size;
  const float* x  = (const float*)d_in[0];
  const float* cp = (const float*)d_in[1];
  const float* sp = (const float*)d_in[2];
  const float* wq = (const float*)d_in[3];
  const float* bq = (const float*)d_in[4];
  const float* wk = (const float*)d_in[5];
  const float* bk = (const float*)d_in[6];
  const float* wv = (const float*)d_in[7];
  const float* bv = (const float*)d_in[8];
  const float* wo = (const float*)d_in[9];
  const float* bo = (const float*)d_in[10];
  float* out = (float*)d_out;

  unsigned short* xbf  = (unsigned short*)d_ws;          // 4M shorts (tiled)
  unsigned short* wqkv = xbf  + (size_t)4 * 1024 * 1024; // 3M (tiled)
  unsigned short* wobf = wqkv + (size_t)3 * 1024 * 1024; // 1M (tiled)
  unsigned short* qbf  = wobf + (size_t)1 * 1024 * 1024; // 4M (bh,s,d) pre-scaled
  unsigned short* kbf  = qbf  + (size_t)4 * 1024 * 1024; // 4M (tiled frag-major)
  unsigned short* vbf  = kbf  + (size_t)4 * 1024 * 1024; // 4M (V^T tiled)
  unsigned short* obf  = vbf  + (size_t)4 * 1024 * 1024; // 4M (tiled frag-major)

  hipLaunchKernelGGL(cast_all_kernel, dim3(4096), dim3(256), 0, stream,
                     x, wq, wk, wv, wo, xbf, wqkv, wobf);

  hipLaunchKernelGGL(qkv_gemm_kernel, dim3(768), dim3(256), 0, stream,
                     xbf, wqkv, bq, bk, bv, cp, sp, qbf, kbf, vbf);
  hipLaunchKernelGGL(flash_kernel, dim3(32, 32), dim3(256), 0, stream,
                     qbf, kbf, vbf, obf);
  hipLaunchKernelGGL(oproj_gemm_kernel, dim3(8, 64), dim3(256), 0, stream,
                     obf, wobf, bo, out);
}